// Round 24
// baseline (219.570 us; speedup 1.0000x reference)
//
#include <hip/hip_runtime.h>
#include <hip/hip_bf16.h>
#include <cstdint>

#define D_MODEL 1024
#define D_FF    4096
#define NHEAD   16
#define DHEAD   64
#define BATCH   2
#define SEQ     2048
#define BT      (BATCH*SEQ)   /* 4096 tokens */
#define QKVLD   (3*D_MODEL)   /* fused QKV row stride */
#define LN_EPS  1e-5f

typedef __bf16 bf16_t;
typedef bf16_t bf16x8 __attribute__((ext_vector_type(8)));
typedef float  f32x4  __attribute__((ext_vector_type(4)));

__device__ __forceinline__ unsigned short f2b(float f){
  bf16_t h = (bf16_t)f;
  return __builtin_bit_cast(unsigned short, h);
}
__device__ __forceinline__ float b2f(unsigned short u){
  return __builtin_bit_cast(float, ((unsigned int)u)<<16);
}

__device__ __forceinline__ void gload16(const void* g, void* l){
  __builtin_amdgcn_global_load_lds(
      (const __attribute__((address_space(1))) unsigned int*)g,
      (__attribute__((address_space(3))) unsigned int*)l, 16, 0, 0);
}

// -------- elementwise f32 -> bf16 (+ fused 3-bias concat in 4 tail blocks) ---
__global__ __launch_bounds__(256) void cvt_f32_bf16(
    const float* __restrict__ in, unsigned short* __restrict__ out, int n,
    const float* __restrict__ bq, const float* __restrict__ bk,
    const float* __restrict__ bv, float* __restrict__ bo){
  int bidx = blockIdx.x;
  int nblk = n >> 10;                     // blocks doing the cvt
  if (bidx >= nblk){                      // tail blocks: bias concat
    int i = (bidx - nblk)*256 + threadIdx.x;
    if (i < D_MODEL){ bo[i]=bq[i]; bo[D_MODEL+i]=bk[i]; bo[2*D_MODEL+i]=bv[i]; }
    return;
  }
  int i = (bidx*256 + threadIdx.x)*4;
  float4 v = *(const float4*)(in + i);
  ushort4 u; u.x=f2b(v.x); u.y=f2b(v.y); u.z=f2b(v.z); u.w=f2b(v.w);
  *(ushort4*)(out + i) = u;
}

// ------- batched 1024x1024 transpose-convert: z selects {wq,wk,wv,wo} --------
__global__ __launch_bounds__(256) void transpose_cvt4(
    const float* __restrict__ s0, const float* __restrict__ s1,
    const float* __restrict__ s2, const float* __restrict__ s3,
    unsigned short* __restrict__ d0, unsigned short* __restrict__ d1,
    unsigned short* __restrict__ d2, unsigned short* __restrict__ d3){
  __shared__ float t[32][33];
  int z = blockIdx.z;
  const float* in = (z==0)?s0:(z==1)?s1:(z==2)?s2:s3;
  unsigned short* out = (z==0)?d0:(z==1)?d1:(z==2)?d2:d3;
  int c0 = blockIdx.x*32, r0 = blockIdx.y*32;
  int tx = threadIdx.x, ty = threadIdx.y;  // 32 x 8
  #pragma unroll
  for (int i=0;i<4;++i){ int r = ty + i*8; t[r][tx] = in[(size_t)(r0+r)*D_MODEL + c0+tx]; }
  __syncthreads();
  #pragma unroll
  for (int i=0;i<4;++i){ int r = ty + i*8; out[(size_t)(c0+r)*D_MODEL + r0+tx] = f2b(t[tx][r]); }
}

// ------- batched w1/w2 transpose-convert: z=0 w1 [1024][4096]; z=1 w2 [4096][1024]
__global__ __launch_bounds__(256) void transpose_cvt2(
    const float* __restrict__ s0, const float* __restrict__ s1,
    unsigned short* __restrict__ d0, unsigned short* __restrict__ d1){
  __shared__ float t[32][33];
  int z = blockIdx.z;
  const float* in = z ? s1 : s0;
  unsigned short* out = z ? d1 : d0;
  int R = z ? D_FF : D_MODEL;
  int C = z ? D_MODEL : D_FF;
  int c0, r0;
  if (z==0){ c0 = blockIdx.x*32; r0 = blockIdx.y*32; }
  else     { c0 = blockIdx.y*32; r0 = blockIdx.x*32; }
  int tx = threadIdx.x, ty = threadIdx.y;  // 32 x 8
  #pragma unroll
  for (int i=0;i<4;++i){ int r = ty + i*8; t[r][tx] = in[(size_t)(r0+r)*C + c0+tx]; }
  __syncthreads();
  #pragma unroll
  for (int i=0;i<4;++i){ int r = ty + i*8; out[(size_t)(c0+r)*R + r0+tx] = f2b(t[tx][r]); }
}

// ---------------- GEMM 128x128 (split-K capable) -----------------------------
// EPI 0: +bias -> bf16   EPI 2: +bias relu -> bf16
// EPI 3: SPLIT-K partial (gridDim.z=2): bf16 partial (no bias) -> outB + z*M*N
template<int EPI>
__global__ __launch_bounds__(512,4) void gemm128(
    const unsigned short* __restrict__ A, const unsigned short* __restrict__ Bt,
    const float* __restrict__ bias, const float* __restrict__ resid,
    float* __restrict__ outF, unsigned short* __restrict__ outB,
    int M, int N, int K){
  __shared__ __attribute__((aligned(16))) unsigned short As[2][128*64];  // 32KB
  __shared__ __attribute__((aligned(16))) unsigned short Bs[2][128*64];  // 32KB
  int tid = threadIdx.x;
  int lane = tid & 63, wave = tid >> 6;
  int lr = lane & 15, lg = lane >> 4;          // lg 0..3
  int row0 = blockIdx.x*128, col0 = blockIdx.y*128;
  int wr = (wave>>2)*64, wc = (wave&3)*32;     // wave tile 64x32
  int x7 = lr & 7;

  int sr = tid >> 3;                           // row within 64-row half
  int sl = (tid & 7) ^ (sr & 7);               // pre-swizzled global slot
  auto STAGE = [&](int k0, int buf){
    #pragma unroll
    for (int it=0; it<2; ++it){
      int c = it*512 + tid;
      int r = it*64 + sr;
      gload16(A  + (size_t)(row0+r)*K + k0 + sl*8, &As[buf][c<<3]);
      gload16(Bt + (size_t)(col0+r)*K + k0 + sl*8, &Bs[buf][c<<3]);
    }
  };

  f32x4 acc[4][2] = {};
  int nk = K >> 6;
  int t0 = 0, t1 = nk;
  if (EPI==3){ int half = nk >> 1; t0 = blockIdx.z*half; t1 = t0 + half; }
  STAGE(t0<<6, 0);
  asm volatile("s_waitcnt vmcnt(0)" ::: "memory");
  __builtin_amdgcn_s_barrier();
  int cur = 0;
  for (int t=t0; t<t1; ++t){
    if (t+1 < t1) STAGE((t+1)<<6, cur^1);      // prefetch issues under compute
    #pragma unroll
    for (int kk=0; kk<2; ++kk){
      int sk = ((kk*4 + lg) ^ x7) << 3;        // swizzled 16B-slot -> halfword offset
      bf16x8 af[4], bfr[2];
      #pragma unroll
      for (int mi=0;mi<4;++mi) af[mi]  = *(const bf16x8*)&As[cur][(wr+mi*16+lr)*64 + sk];
      #pragma unroll
      for (int ni=0;ni<2;++ni) bfr[ni] = *(const bf16x8*)&Bs[cur][(wc+ni*16+lr)*64 + sk];
      #pragma unroll
      for (int mi=0;mi<4;++mi)
        #pragma unroll
        for (int ni=0;ni<2;++ni)
          acc[mi][ni] = __builtin_amdgcn_mfma_f32_16x16x32_bf16(af[mi], bfr[ni], acc[mi][ni], 0,0,0);
    }
    asm volatile("s_waitcnt vmcnt(0)" ::: "memory");  // drain prefetch (issued long ago)
    __builtin_amdgcn_s_barrier();                      // ONE barrier per K-step
    cur ^= 1;
  }
  unsigned short* outBP = (EPI==3) ? (outB + (size_t)blockIdx.z*((size_t)M*N)) : outB;
  #pragma unroll
  for (int mi=0;mi<4;++mi){
    int row = row0 + wr + mi*16 + (lg<<2);
    #pragma unroll
    for (int ni=0;ni<2;++ni){
      int col = col0 + wc + ni*16 + lr;
      float bs = (EPI==3) ? 0.f : bias[col];
      #pragma unroll
      for (int j=0;j<4;++j){
        size_t idx = (size_t)(row+j)*N + col;
        float v = acc[mi][ni][j] + bs;
        if (EPI==3){ outBP[idx] = f2b(v); }
        else if (EPI==2){ v = fmaxf(v, 0.f); outB[idx] = f2b(v); }
        else { outB[idx] = f2b(v); }
      }
    }
  }
}

// ---------------- GEMM 256x256, 8-phase counted-vmcnt (T2+T3+T4+T5) ----------
// EPI 0: +bias -> bf16 (+ optional fused V-transpose when outVt!=nullptr)
// EPI 2: +bias relu -> bf16
// EPI 3: SPLIT-K=4 partial (gridDim.z=4): bf16 partial (no bias) -> outB + z*M*N
template<int EPI>
__global__ __launch_bounds__(512,2) void gemm256(
    const unsigned short* __restrict__ A, const unsigned short* __restrict__ Bt,
    const float* __restrict__ bias, unsigned short* __restrict__ outB,
    unsigned short* __restrict__ outVt,
    int M, int N, int K){
  __shared__ __attribute__((aligned(16))) unsigned short As[2][2][128*64]; // 64KB
  __shared__ __attribute__((aligned(16))) unsigned short Bs[2][2][128*64]; // 64KB
  int tid = threadIdx.x;
  int lane = tid & 63, wave = tid >> 6;
  int lr = lane & 15, lg = lane >> 4;
  int wm = wave >> 2, wn = wave & 3;           // 2M x 4N
  int row0 = blockIdx.x*256, col0 = blockIdx.y*256;
  int x7 = lr & 7;
  int sr = tid >> 3;                           // 0..63
  int sl = (tid & 7) ^ (sr & 7);               // pre-swizzled global slot

  auto STAGE_A = [&](int t, int buf, int h){
    #pragma unroll
    for (int i=0;i<2;++i){
      int c = i*512 + tid;
      int r = i*64 + sr;
      gload16(A + (size_t)(row0 + h*128 + r)*K + t*64 + sl*8, &As[buf][h][c<<3]);
    }
  };
  auto STAGE_B = [&](int t, int buf, int h){
    #pragma unroll
    for (int i=0;i<2;++i){
      int c = i*512 + tid;
      int r = i*64 + sr;
      gload16(Bt + (size_t)(col0 + h*128 + r)*K + t*64 + sl*8, &Bs[buf][h][c<<3]);
    }
  };

  f32x4 acc[8][4] = {};
  int nk = K >> 6;
  int t0 = 0, t1 = nk;
  if (EPI==3){ int quarter = nk >> 2; t0 = blockIdx.z*quarter; t1 = t0 + quarter; }
  STAGE_B(t0,0,0); STAGE_B(t0,0,1); STAGE_A(t0,0,0); STAGE_A(t0,0,1);
  asm volatile("s_waitcnt vmcnt(0)" ::: "memory");
  __builtin_amdgcn_s_barrier();
  int cur = 0;
  int bq = (wn&1)*64;                          // quarter base row within B-half
  for (int t=t0; t<t1; ++t){
    bool pre = (t+1 < t1);
    const unsigned short* Ah = &As[cur][wm][0];
    const unsigned short* Bh = &Bs[cur][wn>>1][0];
    bf16x8 af[4][2], bfr[4][2];
    // ---- P0 ----
    #pragma unroll
    for (int mi=0;mi<4;++mi)
      #pragma unroll
      for (int kk=0;kk<2;++kk)
        af[mi][kk] = *(const bf16x8*)&Ah[(mi*16+lr)*64 + (((kk*4+lg)^x7)<<3)];
    #pragma unroll
    for (int ni=0;ni<2;++ni)
      #pragma unroll
      for (int kk=0;kk<2;++kk)
        bfr[ni][kk] = *(const bf16x8*)&Bh[(bq+ni*16+lr)*64 + (((kk*4+lg)^x7)<<3)];
    if (pre){ STAGE_B(t+1, cur^1, 0);
              asm volatile("s_waitcnt vmcnt(2)" ::: "memory"); }
    else    { asm volatile("s_waitcnt vmcnt(0)" ::: "memory"); }
    __builtin_amdgcn_s_barrier();
    __builtin_amdgcn_s_setprio(1);
    #pragma unroll
    for (int mi=0;mi<4;++mi)
      #pragma unroll
      for (int ni=0;ni<2;++ni)
        #pragma unroll
        for (int kk=0;kk<2;++kk)
          acc[mi][ni] = __builtin_amdgcn_mfma_f32_16x16x32_bf16(af[mi][kk], bfr[ni][kk], acc[mi][ni], 0,0,0);
    __builtin_amdgcn_s_setprio(0);
    __builtin_amdgcn_s_barrier();
    // ---- P1 ----
    #pragma unroll
    for (int ni=2;ni<4;++ni)
      #pragma unroll
      for (int kk=0;kk<2;++kk)
        bfr[ni][kk] = *(const bf16x8*)&Bh[(bq+ni*16+lr)*64 + (((kk*4+lg)^x7)<<3)];
    if (pre) STAGE_B(t+1, cur^1, 1);
    __builtin_amdgcn_s_barrier();
    __builtin_amdgcn_s_setprio(1);
    #pragma unroll
    for (int mi=0;mi<4;++mi)
      #pragma unroll
      for (int ni=2;ni<4;++ni)
        #pragma unroll
        for (int kk=0;kk<2;++kk)
          acc[mi][ni] = __builtin_amdgcn_mfma_f32_16x16x32_bf16(af[mi][kk], bfr[ni][kk], acc[mi][ni], 0,0,0);
    __builtin_amdgcn_s_setprio(0);
    __builtin_amdgcn_s_barrier();
    // ---- P2 ----
    #pragma unroll
    for (int mi=0;mi<4;++mi)
      #pragma unroll
      for (int kk=0;kk<2;++kk)
        af[mi][kk] = *(const bf16x8*)&Ah[((mi+4)*16+lr)*64 + (((kk*4+lg)^x7)<<3)];
    if (pre) STAGE_A(t+1, cur^1, 0);
    __builtin_amdgcn_s_barrier();
    __builtin_amdgcn_s_setprio(1);
    #pragma unroll
    for (int mi=0;mi<4;++mi)
      #pragma unroll
      for (int ni=0;ni<2;++ni)
        #pragma unroll
        for (int kk=0;kk<2;++kk)
          acc[mi+4][ni] = __builtin_amdgcn_mfma_f32_16x16x32_bf16(af[mi][kk], bfr[ni][kk], acc[mi+4][ni], 0,0,0);
    __builtin_amdgcn_s_setprio(0);
    __builtin_amdgcn_s_barrier();
    // ---- P3 ----
    if (pre) STAGE_A(t+1, cur^1, 1);
    __builtin_amdgcn_s_barrier();
    __builtin_amdgcn_s_setprio(1);
    #pragma unroll
    for (int mi=0;mi<4;++mi)
      #pragma unroll
      for (int ni=2;ni<4;++ni)
        #pragma unroll
        for (int kk=0;kk<2;++kk)
          acc[mi+4][ni] = __builtin_amdgcn_mfma_f32_16x16x32_bf16(af[mi][kk], bfr[ni][kk], acc[mi+4][ni], 0,0,0);
    __builtin_amdgcn_s_setprio(0);
    __builtin_amdgcn_s_barrier();
    cur ^= 1;
  }
  // epilogue (+ optional fused V-transpose for QKV's V columns)
  unsigned short* outBP = (EPI==3) ? (outB + (size_t)blockIdx.z*((size_t)M*N)) : outB;
  #pragma unroll
  for (int mi=0;mi<8;++mi){
    int row = row0 + wm*128 + mi*16 + (lg<<2);
    #pragma unroll
    for (int ni=0;ni<4;++ni){
      int col = col0 + wn*64 + ni*16 + lr;
      float bs = (EPI==3) ? 0.f : bias[col];
      ushort4 uu;
      #pragma unroll
      for (int j=0;j<4;++j){
        size_t idx = (size_t)(row+j)*N + col;
        float v = acc[mi][ni][j] + bs;
        if (EPI==2) v = fmaxf(v, 0.f);
        unsigned short us = f2b(v);
        outBP[idx] = us;
        if (j==0) uu.x=us; else if (j==1) uu.y=us; else if (j==2) uu.z=us; else uu.w=us;
      }
      if (EPI==0 && outVt && col >= 2*D_MODEL){
        int vc = col - 2*D_MODEL;            // 0..1023
        int bh = (row>>11)*NHEAD + (vc>>6);  // b*16 + h
        int d  = vc & 63;
        int s  = row & (SEQ-1);              // row ≡ 0 mod 4 -> aligned 8B store
        *(ushort4*)&outVt[((size_t)bh*DHEAD + d)*SEQ + s] = uu;
      }
    }
  }
}

// ---- flash attention: swapped-QK^T + T13 defer-rescale + Q-prescale ---------
__global__ __launch_bounds__(256,2) void attn_k(
    const unsigned short* __restrict__ QKV,
    const unsigned short* __restrict__ Vt, unsigned short* __restrict__ O){
  __shared__ __attribute__((aligned(16))) unsigned short Ks[2][128*64];  // 32KB
  __shared__ __attribute__((aligned(16))) unsigned short Vs[2][64*128];  // 32KB
  __shared__ __attribute__((aligned(16))) unsigned short Ps[4][16*128];  // 16KB
  int tid = threadIdx.x, lane = tid&63, wave = tid>>6;
  int lr = lane&15, lg = lane>>4;
  int bid = blockIdx.x;
  int L = (bid & 7)*64 + (bid >> 3);           // XCD-grouped logical block id
  int qx = L & 15;                             // q-pair index 0..15
  int bh = L >> 4;                             // 0..31
  int b = bh>>4, h = bh&15;
  const int NT = SEQ/64;   // 32 q-tiles (64-wide)
  const float SC2 = 0.18033688011112042f;      // 0.125 * log2(e)

  #pragma unroll 1
  for (int half=0; half<2; ++half){
    int qt = half ? qx : (NT-1 - qx);
    int q0w = qt*64 + wave*16;

    const unsigned short* Qrow = QKV + (size_t)(b*SEQ + q0w + lr)*QKVLD + h*DHEAD;
    bf16x8 qf[2];
    qf[0] = *(const bf16x8*)(Qrow + lg*8);
    qf[1] = *(const bf16x8*)(Qrow + 32 + lg*8);
    // Q-prescale: fold softmax scale into Q (once per block half)
    #pragma unroll
    for (int q8=0;q8<2;++q8)
      #pragma unroll
      for (int e=0;e<8;++e)
        qf[q8][e] = (bf16_t)((float)qf[q8][e] * SC2);

    f32x4 oacc[4] = {};
    float m2 = -1e30f, lsum = 0.f;             // scalars: stats for q-row q0w+lr

    auto STAGE = [&](int t, int buf){
      int kv0 = t*128;
      #pragma unroll
      for (int it=0; it<4; ++it){
        int c = it*256 + tid;               // 0..1023
        int rk = c>>3, slk = (c&7) ^ (rk&7);
        gload16(QKV + (size_t)(b*SEQ + kv0 + rk)*QKVLD + D_MODEL + h*DHEAD + slk*8, &Ks[buf][c<<3]);
        int rv = c>>4, slv = (c&15) ^ (rv&15);
        gload16(Vt + ((size_t)bh*DHEAD + rv)*SEQ + kv0 + slv*8, &Vs[buf][c<<3]);
      }
    };

    int nkv = (qt + 2) >> 1;   // number of 128-wide KV tiles
    STAGE(0, 0);
    asm volatile("s_waitcnt vmcnt(0)" ::: "memory");
    __builtin_amdgcn_s_barrier();
    int cur = 0;
    for (int t=0; t<nkv; ++t){
      if (t+1 < nkv) STAGE(t+1, cur^1);        // prefetch under compute

      int kv0 = t*128;
      f32x4 sacc[8] = {};
      // swapped QK^T: mfma(K, Q) -> S[k = ni*16+lg*4+j][q = lr], log2 domain
      #pragma unroll
      for (int kk=0;kk<2;++kk){
        #pragma unroll
        for (int ni=0;ni<8;++ni){
          int krow = ni*16 + lr;
          bf16x8 kf = *(const bf16x8*)&Ks[cur][krow*64 + (((kk*4+lg) ^ (krow&7))<<3)];
          sacc[ni] = __builtin_amdgcn_mfma_f32_16x16x32_bf16(kf, qf[kk], sacc[ni], 0,0,0);
        }
      }
      // causal mask on diagonal tile only (scores already scaled)
      if (t == nkv-1){
        int qpos = q0w + lr;
        #pragma unroll
        for (int ni=0;ni<8;++ni){
          f32x4 v = sacc[ni];
          #pragma unroll
          for (int j=0;j<4;++j){
            int kpos = kv0 + ni*16 + lg*4 + j;
            if (kpos > qpos) v[j] = -1e30f;
          }
          sacc[ni] = v;
        }
      }
      // in-register row max + 2-shfl cross-lg reduce
      f32x4 vm = sacc[0];
      #pragma unroll
      for (int ni=1;ni<8;++ni)
        #pragma unroll
        for (int j=0;j<4;++j) vm[j] = fmaxf(vm[j], sacc[ni][j]);
      float rm = fmaxf(fmaxf(vm[0],vm[1]), fmaxf(vm[2],vm[3]));
      rm = fmaxf(rm, __shfl_xor(rm, 16));
      rm = fmaxf(rm, __shfl_xor(rm, 32));
      if (__all(rm <= m2)){
        // T13 defer-rescale: no row max grew -> corr == 1 exactly
        f32x4 vs = {};
        #pragma unroll
        for (int ni=0;ni<8;++ni){
          f32x4 p;
          #pragma unroll
          for (int j=0;j<4;++j){ p[j] = exp2f(sacc[ni][j] - m2); vs[j] += p[j]; }
          sacc[ni] = p;
        }
        float rs = (vs[0]+vs[1]) + (vs[2]+vs[3]);
        rs += __shfl_xor(rs, 16);
        rs += __shfl_xor(rs, 32);
        lsum += rs;
      } else {
        float mnew = fmaxf(m2, rm);
        float corr = exp2f(m2 - mnew);
        m2 = mnew;
        f32x4 vs = {};
        #pragma unroll
        for (int ni=0;ni<8;++ni){
          f32x4 p;
          #pragma unroll
          for (int j=0;j<4;++j){ p[j] = exp2f(sacc[ni][j] - mnew); vs[j] += p[j]; }
          sacc[ni] = p;
        }
        float rs = (vs[0]+vs[1]) + (vs[2]+vs[3]);
        rs += __shfl_xor(rs, 16);
        rs += __shfl_xor(rs, 32);
        lsum = lsum*corr + rs;
        #pragma unroll
        for (int j=0;j<4;++j){
          float cj = __shfl(corr, lg*4 + j);
          #pragma unroll
          for (int nd=0; nd<4; ++nd) oacc[nd][j] *= cj;
        }
      }
      // P write: pack j-quad -> ds_write_b64; 16B-slot swizzle ts^lr
      #pragma unroll
      for (int ni=0;ni<8;++ni){
        ushort4 u; u.x=f2b(sacc[ni][0]); u.y=f2b(sacc[ni][1]);
                   u.z=f2b(sacc[ni][2]); u.w=f2b(sacc[ni][3]);
        int ts = ni*2 + (lg>>1);                       // 16B slot 0..15
        int a = lr*128 + (((ts ^ lr))<<3) + ((lg&1)<<2); // ushort offset
        *(uint2*)&Ps[wave][a] = __builtin_bit_cast(uint2, u);
      }
      // PV: pa read with matching swizzle; vf unchanged
      #pragma unroll
      for (int kk=0;kk<4;++kk){
        bf16x8 pa = *(const bf16x8*)&Ps[wave][lr*128 + (((kk*4+lg) ^ lr)<<3)];
        #pragma unroll
        for (int nd=0; nd<4; ++nd){
          int dr = nd*16 + lr;
          bf16x8 vf = *(const bf16x8*)&Vs[cur][dr*128 + (((kk*4+lg) ^ (dr&15))<<3)];
          oacc[nd] = __builtin_amdgcn_mfma_f32_16x16x32_bf16(pa, vf, oacc[nd], 0,0,0);
        }
      }
      asm volatile("s_waitcnt vmcnt(0)" ::: "memory");
      __builtin_amdgcn_s_barrier();                      // ONE barrier per tile
      cur ^= 1;
    }
    // epilogue: 1/l for q-row lg*4+j fetched from lane lg*4+j
    #pragma unroll
    for (int j=0;j<4;++j){
      float lj = __shfl(lsum, lg*4 + j);
      float inv = 1.f / lj;
      int token = b*SEQ + q0w + lg*4 + j;
      #pragma unroll
      for (int nd=0; nd<4; ++nd)
        O[(size_t)token*D_MODEL + h*DHEAD + nd*16 + lr] = f2b(oacc[nd][j]*inv);
    }
  }
}

// ---- LayerNorm over h = sum(NP partials) + bias + resid(bf16) ---------------
// MODE 0: write bf16 (outB) only;  MODE 1: write f32 (outF) only.
template<int MODE, int NP>
__global__ __launch_bounds__(256) void ln_sum_k(
    const unsigned short* __restrict__ P,     // [NP][BT][D_MODEL] bf16 partials
    const float* __restrict__ bias,           // [D_MODEL]
    const unsigned short* __restrict__ residB,// [BT][D_MODEL] bf16
    const float* __restrict__ g, const float* __restrict__ bta,
    float* __restrict__ outF, unsigned short* __restrict__ outB){
  int row = blockIdx.x, tid = threadIdx.x;
  const size_t MN = (size_t)BT*D_MODEL;
  ushort4 rb = ((const ushort4*)(residB + (size_t)row*D_MODEL))[tid];
  float4 bb = ((const float4*)bias)[tid];
  float4 v;
  v.x = bb.x + b2f(rb.x); v.y = bb.y + b2f(rb.y);
  v.z = bb.z + b2f(rb.z); v.w = bb.w + b2f(rb.w);
  #pragma unroll
  for (int p=0; p<NP; ++p){
    ushort4 a = ((const ushort4*)(P + p*MN + (size_t)row*D_MODEL))[tid];
    v.x += b2f(a.x); v.y += b2f(a.y); v.z += b2f(a.z); v.w += b2f(a.w);
  }
  float s = v.x+v.y+v.z+v.w;
  float q = v.x*v.x+v.y*v.y+v.z*v.z+v.w*v.w;
  #pragma unroll
  for (int d=32; d; d>>=1){ s += __shfl_xor(s, d); q += __shfl_xor(q, d); }
  __shared__ float rs[4], rq[4];
  int wave = tid>>6;
  if ((tid&63)==0){ rs[wave]=s; rq[wave]=q; }
  __syncthreads();
  s = rs[0]+rs[1]+rs[2]+rs[3];
  q = rq[0]+rq[1]+rq[2]+rq[3];
  float mu  = s * (1.f/D_MODEL);
  float var = q * (1.f/D_MODEL) - mu*mu;
  float rstd = rsqrtf(var + LN_EPS);
  float4 gg = ((const float4*)g)[tid];
  float4 be = ((const float4*)bta)[tid];
  float o0 = (v.x-mu)*rstd*gg.x + be.x;
  float o1 = (v.y-mu)*rstd*gg.y + be.y;
  float o2 = (v.z-mu)*rstd*gg.z + be.z;
  float o3 = (v.w-mu)*rstd*gg.w + be.w;
  if (MODE==0){
    ushort4 u; u.x=f2b(o0); u.y=f2b(o1); u.z=f2b(o2); u.w=f2b(o3);
    ((ushort4*)(outB + (size_t)row*D_MODEL))[tid] = u;
  } else {
    float4 o; o.x=o0; o.y=o1; o.z=o2; o.w=o3;
    ((float4*)(outF + (size_t)row*D_MODEL))[tid] = o;
  }
}

extern "C" void kernel_launch(void* const* d_in, const int* in_sizes, int n_in,
                              void* d_out, int out_size, void* d_ws, size_t ws_size,
                              hipStream_t stream){
  const float* x  = (const float*)d_in[0];
  const float* wq = (const float*)d_in[2];  const float* bq = (const float*)d_in[3];
  const float* wk = (const float*)d_in[4];  const float* bk = (const float*)d_in[5];
  const float* wv = (const float*)d_in[6];  const float* bv = (const float*)d_in[7];
  const float* wo = (const float*)d_in[8];  const float* bo = (const float*)d_in[9];
  const float* w1 = (const float*)d_in[10]; const float* b1 = (const float*)d_in[11];
  const float* w2 = (const float*)d_in[12]; const float* b2 = (const float*)d_in[13];
  const float* g1 = (const float*)d_in[14]; const float* be1= (const float*)d_in[15];
  const float* g2 = (const float*)d_in[16]; const float* be2= (const float*)d_in[17];

  char* w = (char*)d_ws;
  size_t off = 0;
  auto nxt = [&](size_t bytes)->void*{
    void* p = w + off; off = (off + bytes + 255) & ~(size_t)255; return p;
  };
  unsigned short* xb    = (unsigned short*)nxt((size_t)BT*D_MODEL*2);
  unsigned short* wqkvT = (unsigned short*)nxt((size_t)QKVLD*D_MODEL*2);
  unsigned short* woT   = (unsigned short*)nxt((size_t)D_MODEL*D_MODEL*2);
  unsigned short* w1T   = (unsigned short*)nxt((size_t)D_MODEL*D_FF*2);
  unsigned short* w2T   = (unsigned short*)nxt((size_t)D_MODEL*D_FF*2);
  float*          bqkv  = (float*)nxt((size_t)QKVLD*4);
  unsigned short* QKV   = (unsigned short*)nxt((size_t)BT*QKVLD*2);   // 25.17MB
  unsigned short* VtG   = (unsigned short*)nxt((size_t)BT*D_MODEL*2); //  8.39MB (contiguous after QKV)
  unsigned short* attnb = (unsigned short*)nxt((size_t)BT*D_MODEL*2);
  unsigned short* x1b   = (unsigned short*)nxt((size_t)BT*D_MODEL*2);
  unsigned short* ffn1  = (unsigned short*)nxt((size_t)BT*D_FF*2);
  // wo split-K=2 partials (16.8MB) alias QKV prefix; ffn2 split-K=4 partials
  // (33.55MB) alias QKV+VtG (contiguous, both dead after attn_k; wo partials
  // consumed by ln1 before ffn2's GEMM writes).
  unsigned short* Psum  = QKV;

  dim3 tb(32,8);
  // cvt (4096 blocks) + fused bias-concat (4 tail blocks)
  cvt_f32_bf16<<<(BT*D_MODEL)/1024 + 4, 256, 0, stream>>>(x, xb, BT*D_MODEL, bq, bk, bv, bqkv);
  transpose_cvt4<<<dim3(D_MODEL/32, D_MODEL/32, 4), tb, 0, stream>>>(
      wq, wk, wv, wo,
      wqkvT, wqkvT + D_MODEL*D_MODEL, wqkvT + 2*D_MODEL*D_MODEL, woT);
  transpose_cvt2<<<dim3(D_FF/32, D_MODEL/32, 2), tb, 0, stream>>>(w1, w2, w1T, w2T);

  // fused QKV projection (256^2 8-phase) with fused V-transpose into VtG
  gemm256<0><<<dim3(BT/256, QKVLD/256), 512, 0, stream>>>(xb, wqkvT, bqkv, QKV, VtG, BT, QKVLD, D_MODEL);

  attn_k<<<512, 256, 0, stream>>>(QKV, VtG, attnb);

  // wo projection, split-K=2 -> bf16 partials; reduce fused into ln1
  gemm128<3><<<dim3(BT/128, D_MODEL/128, 2), 512, 0, stream>>>(attnb, woT, nullptr, nullptr, nullptr, Psum, BT, D_MODEL, D_MODEL);
  ln_sum_k<0,2><<<BT, 256, 0, stream>>>(Psum, bo, xb, g1, be1, nullptr, x1b);

  // ffn1: 256^2 8-phase GEMM with fused bias+relu
  gemm256<2><<<dim3(BT/256, D_FF/256), 512, 0, stream>>>(x1b, w1T, b1, ffn1, nullptr, BT, D_FF, D_MODEL);

  // ffn2: 256^2 8-phase GEMM, split-K=4 -> bf16 partials; reduce in ln2
  gemm256<3><<<dim3(BT/256, D_MODEL/256, 4), 512, 0, stream>>>(ffn1, w2T, nullptr, Psum, nullptr, BT, D_MODEL, D_FF);
  ln_sum_k<1,4><<<BT, 256, 0, stream>>>(Psum, b2, x1b, g2, be2, (float*)d_out, nullptr);
}

// Round 25
// 214.469 us; speedup vs baseline: 1.0238x; 1.0238x over previous
//
#include <hip/hip_runtime.h>
#include <hip/hip_bf16.h>
#include <cstdint>

#define D_MODEL 1024
#define D_FF    4096
#define NHEAD   16
#define DHEAD   64
#define BATCH   2
#define SEQ     2048
#define BT      (BATCH*SEQ)   /* 4096 tokens */
#define QKVLD   (3*D_MODEL)   /* fused QKV row stride */
#define LN_EPS  1e-5f

typedef __bf16 bf16_t;
typedef bf16_t bf16x8 __attribute__((ext_vector_type(8)));
typedef float  f32x4  __attribute__((ext_vector_type(4)));

__device__ __forceinline__ unsigned short f2b(float f){
  bf16_t h = (bf16_t)f;
  return __builtin_bit_cast(unsigned short, h);
}
__device__ __forceinline__ float b2f(unsigned short u){
  return __builtin_bit_cast(float, ((unsigned int)u)<<16);
}

__device__ __forceinline__ void gload16(const void* g, void* l){
  __builtin_amdgcn_global_load_lds(
      (const __attribute__((address_space(1))) unsigned int*)g,
      (__attribute__((address_space(3))) unsigned int*)l, 16, 0, 0);
}

// -------- elementwise f32 -> bf16 (+ fused 3-bias concat in 4 tail blocks) ---
__global__ __launch_bounds__(256) void cvt_f32_bf16(
    const float* __restrict__ in, unsigned short* __restrict__ out, int n,
    const float* __restrict__ bq, const float* __restrict__ bk,
    const float* __restrict__ bv, float* __restrict__ bo){
  int bidx = blockIdx.x;
  int nblk = n >> 10;                     // blocks doing the cvt
  if (bidx >= nblk){                      // tail blocks: bias concat
    int i = (bidx - nblk)*256 + threadIdx.x;
    if (i < D_MODEL){ bo[i]=bq[i]; bo[D_MODEL+i]=bk[i]; bo[2*D_MODEL+i]=bv[i]; }
    return;
  }
  int i = (bidx*256 + threadIdx.x)*4;
  float4 v = *(const float4*)(in + i);
  ushort4 u; u.x=f2b(v.x); u.y=f2b(v.y); u.z=f2b(v.z); u.w=f2b(v.w);
  *(ushort4*)(out + i) = u;
}

// ------- batched 1024x1024 transpose-convert: z selects {wq,wk,wv,wo} --------
__global__ __launch_bounds__(256) void transpose_cvt4(
    const float* __restrict__ s0, const float* __restrict__ s1,
    const float* __restrict__ s2, const float* __restrict__ s3,
    unsigned short* __restrict__ d0, unsigned short* __restrict__ d1,
    unsigned short* __restrict__ d2, unsigned short* __restrict__ d3){
  __shared__ float t[32][33];
  int z = blockIdx.z;
  const float* in = (z==0)?s0:(z==1)?s1:(z==2)?s2:s3;
  unsigned short* out = (z==0)?d0:(z==1)?d1:(z==2)?d2:d3;
  int c0 = blockIdx.x*32, r0 = blockIdx.y*32;
  int tx = threadIdx.x, ty = threadIdx.y;  // 32 x 8
  #pragma unroll
  for (int i=0;i<4;++i){ int r = ty + i*8; t[r][tx] = in[(size_t)(r0+r)*D_MODEL + c0+tx]; }
  __syncthreads();
  #pragma unroll
  for (int i=0;i<4;++i){ int r = ty + i*8; out[(size_t)(c0+r)*D_MODEL + r0+tx] = f2b(t[tx][r]); }
}

// ------- batched w1/w2 transpose-convert: z=0 w1 [1024][4096]; z=1 w2 [4096][1024]
__global__ __launch_bounds__(256) void transpose_cvt2(
    const float* __restrict__ s0, const float* __restrict__ s1,
    unsigned short* __restrict__ d0, unsigned short* __restrict__ d1){
  __shared__ float t[32][33];
  int z = blockIdx.z;
  const float* in = z ? s1 : s0;
  unsigned short* out = z ? d1 : d0;
  int R = z ? D_FF : D_MODEL;
  int C = z ? D_MODEL : D_FF;
  int c0, r0;
  if (z==0){ c0 = blockIdx.x*32; r0 = blockIdx.y*32; }
  else     { c0 = blockIdx.y*32; r0 = blockIdx.x*32; }
  int tx = threadIdx.x, ty = threadIdx.y;  // 32 x 8
  #pragma unroll
  for (int i=0;i<4;++i){ int r = ty + i*8; t[r][tx] = in[(size_t)(r0+r)*C + c0+tx]; }
  __syncthreads();
  #pragma unroll
  for (int i=0;i<4;++i){ int r = ty + i*8; out[(size_t)(c0+r)*R + r0+tx] = f2b(t[tx][r]); }
}

// ---------------- GEMM 128x128 (split-K capable) -----------------------------
// EPI 0: +bias -> bf16   EPI 2: +bias relu -> bf16
// EPI 3: SPLIT-K partial (gridDim.z=2): bf16 partial (no bias) -> outB + z*M*N
template<int EPI>
__global__ __launch_bounds__(512,4) void gemm128(
    const unsigned short* __restrict__ A, const unsigned short* __restrict__ Bt,
    const float* __restrict__ bias, const float* __restrict__ resid,
    float* __restrict__ outF, unsigned short* __restrict__ outB,
    int M, int N, int K){
  __shared__ __attribute__((aligned(16))) unsigned short As[2][128*64];  // 32KB
  __shared__ __attribute__((aligned(16))) unsigned short Bs[2][128*64];  // 32KB
  int tid = threadIdx.x;
  int lane = tid & 63, wave = tid >> 6;
  int lr = lane & 15, lg = lane >> 4;          // lg 0..3
  int row0 = blockIdx.x*128, col0 = blockIdx.y*128;
  int wr = (wave>>2)*64, wc = (wave&3)*32;     // wave tile 64x32
  int x7 = lr & 7;

  int sr = tid >> 3;                           // row within 64-row half
  int sl = (tid & 7) ^ (sr & 7);               // pre-swizzled global slot
  auto STAGE = [&](int k0, int buf){
    #pragma unroll
    for (int it=0; it<2; ++it){
      int c = it*512 + tid;
      int r = it*64 + sr;
      gload16(A  + (size_t)(row0+r)*K + k0 + sl*8, &As[buf][c<<3]);
      gload16(Bt + (size_t)(col0+r)*K + k0 + sl*8, &Bs[buf][c<<3]);
    }
  };

  f32x4 acc[4][2] = {};
  int nk = K >> 6;
  int t0 = 0, t1 = nk;
  if (EPI==3){ int half = nk >> 1; t0 = blockIdx.z*half; t1 = t0 + half; }
  STAGE(t0<<6, 0);
  asm volatile("s_waitcnt vmcnt(0)" ::: "memory");
  __builtin_amdgcn_s_barrier();
  int cur = 0;
  for (int t=t0; t<t1; ++t){
    if (t+1 < t1) STAGE((t+1)<<6, cur^1);      // prefetch issues under compute
    #pragma unroll
    for (int kk=0; kk<2; ++kk){
      int sk = ((kk*4 + lg) ^ x7) << 3;        // swizzled 16B-slot -> halfword offset
      bf16x8 af[4], bfr[2];
      #pragma unroll
      for (int mi=0;mi<4;++mi) af[mi]  = *(const bf16x8*)&As[cur][(wr+mi*16+lr)*64 + sk];
      #pragma unroll
      for (int ni=0;ni<2;++ni) bfr[ni] = *(const bf16x8*)&Bs[cur][(wc+ni*16+lr)*64 + sk];
      #pragma unroll
      for (int mi=0;mi<4;++mi)
        #pragma unroll
        for (int ni=0;ni<2;++ni)
          acc[mi][ni] = __builtin_amdgcn_mfma_f32_16x16x32_bf16(af[mi], bfr[ni], acc[mi][ni], 0,0,0);
    }
    asm volatile("s_waitcnt vmcnt(0)" ::: "memory");  // drain prefetch (issued long ago)
    __builtin_amdgcn_s_barrier();                      // ONE barrier per K-step
    cur ^= 1;
  }
  unsigned short* outBP = (EPI==3) ? (outB + (size_t)blockIdx.z*((size_t)M*N)) : outB;
  #pragma unroll
  for (int mi=0;mi<4;++mi){
    int row = row0 + wr + mi*16 + (lg<<2);
    #pragma unroll
    for (int ni=0;ni<2;++ni){
      int col = col0 + wc + ni*16 + lr;
      float bs = (EPI==3) ? 0.f : bias[col];
      #pragma unroll
      for (int j=0;j<4;++j){
        size_t idx = (size_t)(row+j)*N + col;
        float v = acc[mi][ni][j] + bs;
        if (EPI==3){ outBP[idx] = f2b(v); }
        else if (EPI==2){ v = fmaxf(v, 0.f); outB[idx] = f2b(v); }
        else { outB[idx] = f2b(v); }
      }
    }
  }
}

// ---------------- GEMM 256x256, 8-phase counted-vmcnt (T2+T3+T4+T5) ----------
// EPI 0: +bias -> bf16 (+ optional fused V-transpose when outVt!=nullptr)
// EPI 2: +bias relu -> bf16
template<int EPI>
__global__ __launch_bounds__(512,2) void gemm256(
    const unsigned short* __restrict__ A, const unsigned short* __restrict__ Bt,
    const float* __restrict__ bias, unsigned short* __restrict__ outB,
    unsigned short* __restrict__ outVt,
    int M, int N, int K){
  __shared__ __attribute__((aligned(16))) unsigned short As[2][2][128*64]; // 64KB
  __shared__ __attribute__((aligned(16))) unsigned short Bs[2][2][128*64]; // 64KB
  int tid = threadIdx.x;
  int lane = tid & 63, wave = tid >> 6;
  int lr = lane & 15, lg = lane >> 4;
  int wm = wave >> 2, wn = wave & 3;           // 2M x 4N
  int row0 = blockIdx.x*256, col0 = blockIdx.y*256;
  int x7 = lr & 7;
  int sr = tid >> 3;                           // 0..63
  int sl = (tid & 7) ^ (sr & 7);               // pre-swizzled global slot

  auto STAGE_A = [&](int t, int buf, int h){
    #pragma unroll
    for (int i=0;i<2;++i){
      int c = i*512 + tid;
      int r = i*64 + sr;
      gload16(A + (size_t)(row0 + h*128 + r)*K + t*64 + sl*8, &As[buf][h][c<<3]);
    }
  };
  auto STAGE_B = [&](int t, int buf, int h){
    #pragma unroll
    for (int i=0;i<2;++i){
      int c = i*512 + tid;
      int r = i*64 + sr;
      gload16(Bt + (size_t)(col0 + h*128 + r)*K + t*64 + sl*8, &Bs[buf][h][c<<3]);
    }
  };

  f32x4 acc[8][4] = {};
  int nk = K >> 6;
  STAGE_B(0,0,0); STAGE_B(0,0,1); STAGE_A(0,0,0); STAGE_A(0,0,1);
  asm volatile("s_waitcnt vmcnt(0)" ::: "memory");
  __builtin_amdgcn_s_barrier();
  int cur = 0;
  int bq = (wn&1)*64;                          // quarter base row within B-half
  for (int t=0; t<nk; ++t){
    bool pre = (t+1 < nk);
    const unsigned short* Ah = &As[cur][wm][0];
    const unsigned short* Bh = &Bs[cur][wn>>1][0];
    bf16x8 af[4][2], bfr[4][2];
    // ---- P0 ----
    #pragma unroll
    for (int mi=0;mi<4;++mi)
      #pragma unroll
      for (int kk=0;kk<2;++kk)
        af[mi][kk] = *(const bf16x8*)&Ah[(mi*16+lr)*64 + (((kk*4+lg)^x7)<<3)];
    #pragma unroll
    for (int ni=0;ni<2;++ni)
      #pragma unroll
      for (int kk=0;kk<2;++kk)
        bfr[ni][kk] = *(const bf16x8*)&Bh[(bq+ni*16+lr)*64 + (((kk*4+lg)^x7)<<3)];
    if (pre){ STAGE_B(t+1, cur^1, 0);
              asm volatile("s_waitcnt vmcnt(2)" ::: "memory"); }
    else    { asm volatile("s_waitcnt vmcnt(0)" ::: "memory"); }
    __builtin_amdgcn_s_barrier();
    __builtin_amdgcn_s_setprio(1);
    #pragma unroll
    for (int mi=0;mi<4;++mi)
      #pragma unroll
      for (int ni=0;ni<2;++ni)
        #pragma unroll
        for (int kk=0;kk<2;++kk)
          acc[mi][ni] = __builtin_amdgcn_mfma_f32_16x16x32_bf16(af[mi][kk], bfr[ni][kk], acc[mi][ni], 0,0,0);
    __builtin_amdgcn_s_setprio(0);
    __builtin_amdgcn_s_barrier();
    // ---- P1 ----
    #pragma unroll
    for (int ni=2;ni<4;++ni)
      #pragma unroll
      for (int kk=0;kk<2;++kk)
        bfr[ni][kk] = *(const bf16x8*)&Bh[(bq+ni*16+lr)*64 + (((kk*4+lg)^x7)<<3)];
    if (pre) STAGE_B(t+1, cur^1, 1);
    __builtin_amdgcn_s_barrier();
    __builtin_amdgcn_s_setprio(1);
    #pragma unroll
    for (int mi=0;mi<4;++mi)
      #pragma unroll
      for (int ni=2;ni<4;++ni)
        #pragma unroll
        for (int kk=0;kk<2;++kk)
          acc[mi][ni] = __builtin_amdgcn_mfma_f32_16x16x32_bf16(af[mi][kk], bfr[ni][kk], acc[mi][ni], 0,0,0);
    __builtin_amdgcn_s_setprio(0);
    __builtin_amdgcn_s_barrier();
    // ---- P2 ----
    #pragma unroll
    for (int mi=0;mi<4;++mi)
      #pragma unroll
      for (int kk=0;kk<2;++kk)
        af[mi][kk] = *(const bf16x8*)&Ah[((mi+4)*16+lr)*64 + (((kk*4+lg)^x7)<<3)];
    if (pre) STAGE_A(t+1, cur^1, 0);
    __builtin_amdgcn_s_barrier();
    __builtin_amdgcn_s_setprio(1);
    #pragma unroll
    for (int mi=0;mi<4;++mi)
      #pragma unroll
      for (int ni=0;ni<2;++ni)
        #pragma unroll
        for (int kk=0;kk<2;++kk)
          acc[mi+4][ni] = __builtin_amdgcn_mfma_f32_16x16x32_bf16(af[mi][kk], bfr[ni][kk], acc[mi+4][ni], 0,0,0);
    __builtin_amdgcn_s_setprio(0);
    __builtin_amdgcn_s_barrier();
    // ---- P3 ----
    if (pre) STAGE_A(t+1, cur^1, 1);
    __builtin_amdgcn_s_barrier();
    __builtin_amdgcn_s_setprio(1);
    #pragma unroll
    for (int mi=0;mi<4;++mi)
      #pragma unroll
      for (int ni=2;ni<4;++ni)
        #pragma unroll
        for (int kk=0;kk<2;++kk)
          acc[mi+4][ni] = __builtin_amdgcn_mfma_f32_16x16x32_bf16(af[mi][kk], bfr[ni][kk], acc[mi+4][ni], 0,0,0);
    __builtin_amdgcn_s_setprio(0);
    __builtin_amdgcn_s_barrier();
    cur ^= 1;
  }
  // epilogue (+ optional fused V-transpose for QKV's V columns)
  #pragma unroll
  for (int mi=0;mi<8;++mi){
    int row = row0 + wm*128 + mi*16 + (lg<<2);
    #pragma unroll
    for (int ni=0;ni<4;++ni){
      int col = col0 + wn*64 + ni*16 + lr;
      float bs = bias[col];
      ushort4 uu;
      #pragma unroll
      for (int j=0;j<4;++j){
        size_t idx = (size_t)(row+j)*N + col;
        float v = acc[mi][ni][j] + bs;
        if (EPI==2) v = fmaxf(v, 0.f);
        unsigned short us = f2b(v);
        outB[idx] = us;
        if (j==0) uu.x=us; else if (j==1) uu.y=us; else if (j==2) uu.z=us; else uu.w=us;
      }
      if (EPI==0 && outVt && col >= 2*D_MODEL){
        int vc = col - 2*D_MODEL;            // 0..1023
        int bh = (row>>11)*NHEAD + (vc>>6);  // b*16 + h
        int d  = vc & 63;
        int s  = row & (SEQ-1);              // row ≡ 0 mod 4 -> aligned 8B store
        *(ushort4*)&outVt[((size_t)bh*DHEAD + d)*SEQ + s] = uu;
      }
    }
  }
}

// ---- flash attention: swapped-QK^T + T13 defer-rescale + Q-prescale ---------
__global__ __launch_bounds__(256,2) void attn_k(
    const unsigned short* __restrict__ QKV,
    const unsigned short* __restrict__ Vt, unsigned short* __restrict__ O){
  __shared__ __attribute__((aligned(16))) unsigned short Ks[2][128*64];  // 32KB
  __shared__ __attribute__((aligned(16))) unsigned short Vs[2][64*128];  // 32KB
  __shared__ __attribute__((aligned(16))) unsigned short Ps[4][16*128];  // 16KB
  int tid = threadIdx.x, lane = tid&63, wave = tid>>6;
  int lr = lane&15, lg = lane>>4;
  int bid = blockIdx.x;
  int L = (bid & 7)*64 + (bid >> 3);           // XCD-grouped logical block id
  int qx = L & 15;                             // q-pair index 0..15
  int bh = L >> 4;                             // 0..31
  int b = bh>>4, h = bh&15;
  const int NT = SEQ/64;   // 32 q-tiles (64-wide)
  const float SC2 = 0.18033688011112042f;      // 0.125 * log2(e)

  #pragma unroll 1
  for (int half=0; half<2; ++half){
    int qt = half ? qx : (NT-1 - qx);
    int q0w = qt*64 + wave*16;

    const unsigned short* Qrow = QKV + (size_t)(b*SEQ + q0w + lr)*QKVLD + h*DHEAD;
    bf16x8 qf[2];
    qf[0] = *(const bf16x8*)(Qrow + lg*8);
    qf[1] = *(const bf16x8*)(Qrow + 32 + lg*8);
    // Q-prescale: fold softmax scale into Q (once per block half)
    #pragma unroll
    for (int q8=0;q8<2;++q8)
      #pragma unroll
      for (int e=0;e<8;++e)
        qf[q8][e] = (bf16_t)((float)qf[q8][e] * SC2);

    f32x4 oacc[4] = {};
    float m2 = -1e30f, lsum = 0.f;             // scalars: stats for q-row q0w+lr

    auto STAGE = [&](int t, int buf){
      int kv0 = t*128;
      #pragma unroll
      for (int it=0; it<4; ++it){
        int c = it*256 + tid;               // 0..1023
        int rk = c>>3, slk = (c&7) ^ (rk&7);
        gload16(QKV + (size_t)(b*SEQ + kv0 + rk)*QKVLD + D_MODEL + h*DHEAD + slk*8, &Ks[buf][c<<3]);
        int rv = c>>4, slv = (c&15) ^ (rv&15);
        gload16(Vt + ((size_t)bh*DHEAD + rv)*SEQ + kv0 + slv*8, &Vs[buf][c<<3]);
      }
    };

    int nkv = (qt + 2) >> 1;   // number of 128-wide KV tiles
    STAGE(0, 0);
    asm volatile("s_waitcnt vmcnt(0)" ::: "memory");
    __builtin_amdgcn_s_barrier();
    int cur = 0;
    for (int t=0; t<nkv; ++t){
      if (t+1 < nkv) STAGE(t+1, cur^1);        // prefetch under compute

      int kv0 = t*128;
      f32x4 sacc[8] = {};
      // swapped QK^T: mfma(K, Q) -> S[k = ni*16+lg*4+j][q = lr], log2 domain
      #pragma unroll
      for (int kk=0;kk<2;++kk){
        #pragma unroll
        for (int ni=0;ni<8;++ni){
          int krow = ni*16 + lr;
          bf16x8 kf = *(const bf16x8*)&Ks[cur][krow*64 + (((kk*4+lg) ^ (krow&7))<<3)];
          sacc[ni] = __builtin_amdgcn_mfma_f32_16x16x32_bf16(kf, qf[kk], sacc[ni], 0,0,0);
        }
      }
      // causal mask on diagonal tile only (scores already scaled)
      if (t == nkv-1){
        int qpos = q0w + lr;
        #pragma unroll
        for (int ni=0;ni<8;++ni){
          f32x4 v = sacc[ni];
          #pragma unroll
          for (int j=0;j<4;++j){
            int kpos = kv0 + ni*16 + lg*4 + j;
            if (kpos > qpos) v[j] = -1e30f;
          }
          sacc[ni] = v;
        }
      }
      // in-register row max + 2-shfl cross-lg reduce
      f32x4 vm = sacc[0];
      #pragma unroll
      for (int ni=1;ni<8;++ni)
        #pragma unroll
        for (int j=0;j<4;++j) vm[j] = fmaxf(vm[j], sacc[ni][j]);
      float rm = fmaxf(fmaxf(vm[0],vm[1]), fmaxf(vm[2],vm[3]));
      rm = fmaxf(rm, __shfl_xor(rm, 16));
      rm = fmaxf(rm, __shfl_xor(rm, 32));
      if (__all(rm <= m2)){
        // T13 defer-rescale: no row max grew -> corr == 1 exactly
        f32x4 vs = {};
        #pragma unroll
        for (int ni=0;ni<8;++ni){
          f32x4 p;
          #pragma unroll
          for (int j=0;j<4;++j){ p[j] = exp2f(sacc[ni][j] - m2); vs[j] += p[j]; }
          sacc[ni] = p;
        }
        float rs = (vs[0]+vs[1]) + (vs[2]+vs[3]);
        rs += __shfl_xor(rs, 16);
        rs += __shfl_xor(rs, 32);
        lsum += rs;
      } else {
        float mnew = fmaxf(m2, rm);
        float corr = exp2f(m2 - mnew);
        m2 = mnew;
        f32x4 vs = {};
        #pragma unroll
        for (int ni=0;ni<8;++ni){
          f32x4 p;
          #pragma unroll
          for (int j=0;j<4;++j){ p[j] = exp2f(sacc[ni][j] - mnew); vs[j] += p[j]; }
          sacc[ni] = p;
        }
        float rs = (vs[0]+vs[1]) + (vs[2]+vs[3]);
        rs += __shfl_xor(rs, 16);
        rs += __shfl_xor(rs, 32);
        lsum = lsum*corr + rs;
        #pragma unroll
        for (int j=0;j<4;++j){
          float cj = __shfl(corr, lg*4 + j);
          #pragma unroll
          for (int nd=0; nd<4; ++nd) oacc[nd][j] *= cj;
        }
      }
      // P write: pack j-quad -> ds_write_b64; 16B-slot swizzle ts^lr
      #pragma unroll
      for (int ni=0;ni<8;++ni){
        ushort4 u; u.x=f2b(sacc[ni][0]); u.y=f2b(sacc[ni][1]);
                   u.z=f2b(sacc[ni][2]); u.w=f2b(sacc[ni][3]);
        int ts = ni*2 + (lg>>1);                       // 16B slot 0..15
        int a = lr*128 + (((ts ^ lr))<<3) + ((lg&1)<<2); // ushort offset
        *(uint2*)&Ps[wave][a] = __builtin_bit_cast(uint2, u);
      }
      // PV: pa read with matching swizzle; vf unchanged
      #pragma unroll
      for (int kk=0;kk<4;++kk){
        bf16x8 pa = *(const bf16x8*)&Ps[wave][lr*128 + (((kk*4+lg) ^ lr)<<3)];
        #pragma unroll
        for (int nd=0; nd<4; ++nd){
          int dr = nd*16 + lr;
          bf16x8 vf = *(const bf16x8*)&Vs[cur][dr*128 + (((kk*4+lg) ^ (dr&15))<<3)];
          oacc[nd] = __builtin_amdgcn_mfma_f32_16x16x32_bf16(pa, vf, oacc[nd], 0,0,0);
        }
      }
      asm volatile("s_waitcnt vmcnt(0)" ::: "memory");
      __builtin_amdgcn_s_barrier();                      // ONE barrier per tile
      cur ^= 1;
    }
    // epilogue: 1/l for q-row lg*4+j fetched from lane lg*4+j
    #pragma unroll
    for (int j=0;j<4;++j){
      float lj = __shfl(lsum, lg*4 + j);
      float inv = 1.f / lj;
      int token = b*SEQ + q0w + lg*4 + j;
      #pragma unroll
      for (int nd=0; nd<4; ++nd)
        O[(size_t)token*D_MODEL + h*DHEAD + nd*16 + lr] = f2b(oacc[nd][j]*inv);
    }
  }
}

// ---- LayerNorm over h = P0 + P1 + bias + resid(bf16) ------------------------
// MODE 0: write bf16 (outB) only;  MODE 1: write f32 (outF) only.
template<int MODE>
__global__ __launch_bounds__(256) void ln_sum_k(
    const unsigned short* __restrict__ P,     // [2][BT][D_MODEL] bf16 partials
    const float* __restrict__ bias,           // [D_MODEL]
    const unsigned short* __restrict__ residB,// [BT][D_MODEL] bf16
    const float* __restrict__ g, const float* __restrict__ bta,
    float* __restrict__ outF, unsigned short* __restrict__ outB){
  int row = blockIdx.x, tid = threadIdx.x;
  const size_t MN = (size_t)BT*D_MODEL;
  ushort4 a0 = ((const ushort4*)(P + (size_t)row*D_MODEL))[tid];
  ushort4 a1 = ((const ushort4*)(P + MN + (size_t)row*D_MODEL))[tid];
  ushort4 rb = ((const ushort4*)(residB + (size_t)row*D_MODEL))[tid];
  float4 bb = ((const float4*)bias)[tid];
  float4 v;
  v.x = b2f(a0.x)+b2f(a1.x)+bb.x+b2f(rb.x);
  v.y = b2f(a0.y)+b2f(a1.y)+bb.y+b2f(rb.y);
  v.z = b2f(a0.z)+b2f(a1.z)+bb.z+b2f(rb.z);
  v.w = b2f(a0.w)+b2f(a1.w)+bb.w+b2f(rb.w);
  float s = v.x+v.y+v.z+v.w;
  float q = v.x*v.x+v.y*v.y+v.z*v.z+v.w*v.w;
  #pragma unroll
  for (int d=32; d; d>>=1){ s += __shfl_xor(s, d); q += __shfl_xor(q, d); }
  __shared__ float rs[4], rq[4];
  int wave = tid>>6;
  if ((tid&63)==0){ rs[wave]=s; rq[wave]=q; }
  __syncthreads();
  s = rs[0]+rs[1]+rs[2]+rs[3];
  q = rq[0]+rq[1]+rq[2]+rq[3];
  float mu  = s * (1.f/D_MODEL);
  float var = q * (1.f/D_MODEL) - mu*mu;
  float rstd = rsqrtf(var + LN_EPS);
  float4 gg = ((const float4*)g)[tid];
  float4 be = ((const float4*)bta)[tid];
  float o0 = (v.x-mu)*rstd*gg.x + be.x;
  float o1 = (v.y-mu)*rstd*gg.y + be.y;
  float o2 = (v.z-mu)*rstd*gg.z + be.z;
  float o3 = (v.w-mu)*rstd*gg.w + be.w;
  if (MODE==0){
    ushort4 u; u.x=f2b(o0); u.y=f2b(o1); u.z=f2b(o2); u.w=f2b(o3);
    ((ushort4*)(outB + (size_t)row*D_MODEL))[tid] = u;
  } else {
    float4 o; o.x=o0; o.y=o1; o.z=o2; o.w=o3;
    ((float4*)(outF + (size_t)row*D_MODEL))[tid] = o;
  }
}

extern "C" void kernel_launch(void* const* d_in, const int* in_sizes, int n_in,
                              void* d_out, int out_size, void* d_ws, size_t ws_size,
                              hipStream_t stream){
  const float* x  = (const float*)d_in[0];
  const float* wq = (const float*)d_in[2];  const float* bq = (const float*)d_in[3];
  const float* wk = (const float*)d_in[4];  const float* bk = (const float*)d_in[5];
  const float* wv = (const float*)d_in[6];  const float* bv = (const float*)d_in[7];
  const float* wo = (const float*)d_in[8];  const float* bo = (const float*)d_in[9];
  const float* w1 = (const float*)d_in[10]; const float* b1 = (const float*)d_in[11];
  const float* w2 = (const float*)d_in[12]; const float* b2 = (const float*)d_in[13];
  const float* g1 = (const float*)d_in[14]; const float* be1= (const float*)d_in[15];
  const float* g2 = (const float*)d_in[16]; const float* be2= (const float*)d_in[17];

  char* w = (char*)d_ws;
  size_t off = 0;
  auto nxt = [&](size_t bytes)->void*{
    void* p = w + off; off = (off + bytes + 255) & ~(size_t)255; return p;
  };
  unsigned short* xb    = (unsigned short*)nxt((size_t)BT*D_MODEL*2);
  unsigned short* wqkvT = (unsigned short*)nxt((size_t)QKVLD*D_MODEL*2);
  unsigned short* woT   = (unsigned short*)nxt((size_t)D_MODEL*D_MODEL*2);
  unsigned short* w1T   = (unsigned short*)nxt((size_t)D_MODEL*D_FF*2);
  unsigned short* w2T   = (unsigned short*)nxt((size_t)D_MODEL*D_FF*2);
  float*          bqkv  = (float*)nxt((size_t)QKVLD*4);
  unsigned short* QKV   = (unsigned short*)nxt((size_t)BT*QKVLD*2);   // 25.17MB
  unsigned short* VtG   = (unsigned short*)nxt((size_t)BT*D_MODEL*2); //  8.39MB
  unsigned short* attnb = (unsigned short*)nxt((size_t)BT*D_MODEL*2);
  unsigned short* x1b   = (unsigned short*)nxt((size_t)BT*D_MODEL*2);
  unsigned short* ffn1  = (unsigned short*)nxt((size_t)BT*D_FF*2);
  // split-K bf16 partials [2][BT][D_MODEL] = 16.8MB alias the dead QKV region:
  // QKV last read by attn_k; partials first written by the wo-GEMM afterwards.
  unsigned short* Psum  = QKV;

  dim3 tb(32,8);
  // cvt (4096 blocks) + fused bias-concat (4 tail blocks)
  cvt_f32_bf16<<<(BT*D_MODEL)/1024 + 4, 256, 0, stream>>>(x, xb, BT*D_MODEL, bq, bk, bv, bqkv);
  transpose_cvt4<<<dim3(D_MODEL/32, D_MODEL/32, 4), tb, 0, stream>>>(
      wq, wk, wv, wo,
      wqkvT, wqkvT + D_MODEL*D_MODEL, wqkvT + 2*D_MODEL*D_MODEL, woT);
  transpose_cvt2<<<dim3(D_FF/32, D_MODEL/32, 2), tb, 0, stream>>>(w1, w2, w1T, w2T);

  // fused QKV projection (256^2 8-phase) with fused V-transpose into VtG
  gemm256<0><<<dim3(BT/256, QKVLD/256), 512, 0, stream>>>(xb, wqkvT, bqkv, QKV, VtG, BT, QKVLD, D_MODEL);

  attn_k<<<512, 256, 0, stream>>>(QKV, VtG, attnb);

  // wo projection, split-K=2 -> bf16 partials; reduce fused into ln1
  gemm128<3><<<dim3(BT/128, D_MODEL/128, 2), 512, 0, stream>>>(attnb, woT, nullptr, nullptr, nullptr, Psum, BT, D_MODEL, D_MODEL);
  ln_sum_k<0><<<BT, 256, 0, stream>>>(Psum, bo, xb, g1, be1, nullptr, x1b);

  // ffn1: 256^2 8-phase GEMM with fused bias+relu
  gemm256<2><<<dim3(BT/256, D_FF/256), 512, 0, stream>>>(x1b, w1T, b1, ffn1, nullptr, BT, D_FF, D_MODEL);

  // ffn2, split-K=2 -> bf16 partials (same region, dead after ln1); reduce in ln2
  gemm128<3><<<dim3(BT/128, D_MODEL/128, 2), 512, 0, stream>>>(ffn1, w2T, nullptr, nullptr, nullptr, Psum, BT, D_MODEL, D_FF);
  ln_sum_k<1><<<BT, 256, 0, stream>>>(Psum, b2, x1b, g2, be2, (float*)d_out, nullptr);
}